// Round 2
// baseline (359.312 us; speedup 1.0000x reference)
//
#include <hip/hip_runtime.h>
#include <hip/hip_bf16.h>

// ---------------------------------------------------------------------------
// TransD-style scoring:
//   score[b] = || rp*(hp.h) + sum(h) + r - rp*(tp.t) - sum(t) ||^2
// With a = hp.h - tp.t, c = sum(h) - sum(t):
//   score = a^2*S_pp + c^2*D + S_rr + 2ac*S_p + 2a*S_pr + 2c*S_r
// Pass 1 computes per-node (sum, dot); pass 2 per-relation sums; pass 3 scores.
//
// R2 changes (theory: pass1 was latency-bound — 10-shuffle dep chain per 2KB,
// VALUBusy 17%, eff. read 3.6 TB/s of 6.3 ceiling):
//  - pass1: 8 lanes/row -> 8 rows/wave, 8x 1KB loads in flight, 6 shuffles
//    per 8 rows (was 40), 64B coalesced store per wave.
//  - pass3: 4 elements/thread for gather MLP; rstats as float4+scalar.
// ---------------------------------------------------------------------------

#define ENT_DIM 128

// Pass 1: per-node (sum, dot). lane = sub*8 + chunk; sub = row within the
// wave's 8-row group, chunk = which of 8 float4-columns this lane sweeps
// (stride 8 float4s, 4 iterations covers the 32-float4 row).
__global__ void node_stats_kernel(const float* __restrict__ he,
                                  const float* __restrict__ hep,
                                  const float* __restrict__ te,
                                  const float* __restrict__ tep,
                                  float2* __restrict__ hstats,
                                  float2* __restrict__ tstats,
                                  int n_nodes) {
    const int wave  = (blockIdx.x * blockDim.x + threadIdx.x) >> 6;
    const int lane  = threadIdx.x & 63;
    const int sub   = lane >> 3;   // 0..7 row in group
    const int chunk = lane & 7;    // 0..7 float4 column
    const int njobs = 2 * n_nodes;

    const int job = wave * 8 + sub;
    if (job >= njobs) return;

    const bool is_head = job < n_nodes;
    const int node = is_head ? job : job - n_nodes;
    const float* emb  = is_head ? he  : te;
    const float* embp = is_head ? hep : tep;
    float2* st = is_head ? hstats : tstats;

    const float4* pe  = (const float4*)(emb  + (size_t)node * ENT_DIM) + chunk;
    const float4* pep = (const float4*)(embp + (size_t)node * ENT_DIM) + chunk;

    float4 v[4], vp[4];
    #pragma unroll
    for (int k = 0; k < 4; ++k) v[k]  = pe[k * 8];
    #pragma unroll
    for (int k = 0; k < 4; ++k) vp[k] = pep[k * 8];

    float s = 0.0f, d = 0.0f;
    #pragma unroll
    for (int k = 0; k < 4; ++k) {
        s += (v[k].x + v[k].y) + (v[k].z + v[k].w);
        d += v[k].x * vp[k].x + v[k].y * vp[k].y
           + v[k].z * vp[k].z + v[k].w * vp[k].w;
    }
    // reduce across the 8-lane group (xor masks 1,2,4 stay within group)
    #pragma unroll
    for (int off = 4; off >= 1; off >>= 1) {
        s += __shfl_xor(s, off, 64);
        d += __shfl_xor(d, off, 64);
    }
    if (chunk == 0) st[node] = make_float2(s, d);
}

// Pass 2: per-relation sums. One wave per relation (only 500).
// Layout per relation (8 floats, 32B): [S_pp, S_p, S_pr, S_r | S_rr, 0,0,0]
__global__ void rel_stats_kernel(const float* __restrict__ re,
                                 const float* __restrict__ rep,
                                 float* __restrict__ rstats, int n_rels) {
    const int wave = (blockIdx.x * blockDim.x + threadIdx.x) >> 6;
    const int lane = threadIdx.x & 63;
    if (wave >= n_rels) return;

    const float2 r = ((const float2*)(re  + (size_t)wave * ENT_DIM))[lane];
    const float2 p = ((const float2*)(rep + (size_t)wave * ENT_DIM))[lane];
    float s_pp = p.x * p.x + p.y * p.y;
    float s_p  = p.x + p.y;
    float s_pr = p.x * r.x + p.y * r.y;
    float s_r  = r.x + r.y;
    float s_rr = r.x * r.x + r.y * r.y;
    #pragma unroll
    for (int off = 32; off >= 1; off >>= 1) {
        s_pp += __shfl_xor(s_pp, off, 64);
        s_p  += __shfl_xor(s_p,  off, 64);
        s_pr += __shfl_xor(s_pr, off, 64);
        s_r  += __shfl_xor(s_r,  off, 64);
        s_rr += __shfl_xor(s_rr, off, 64);
    }
    if (lane == 0) {
        float* o = rstats + (size_t)wave * 8;
        o[0] = s_pp; o[1] = s_p; o[2] = s_pr; o[3] = s_r; o[4] = s_rr;
    }
}

// Pass 3: 4 elements per thread for memory-level parallelism on the gathers.
__global__ void score_kernel(const int* __restrict__ hidx,
                             const int* __restrict__ tidx,
                             const int* __restrict__ ridx,
                             const float2* __restrict__ hstats,
                             const float2* __restrict__ tstats,
                             const float* __restrict__ rstats,
                             float* __restrict__ out, int B) {
    const int t = blockIdx.x * blockDim.x + threadIdx.x;
    const int T = gridDim.x * blockDim.x;

    int hi[4], ti[4], ri[4];
    bool act[4];
    #pragma unroll
    for (int u = 0; u < 4; ++u) {
        const int b = t + u * T;
        act[u] = b < B;
        if (act[u]) { hi[u] = hidx[b]; ti[u] = tidx[b]; ri[u] = ridx[b]; }
    }
    float2 hs[4], ts[4];
    float4 q0[4];
    float  q4[4];
    #pragma unroll
    for (int u = 0; u < 4; ++u) {
        if (act[u]) {
            hs[u] = hstats[hi[u]];
            ts[u] = tstats[ti[u]];
            const float* q = rstats + (size_t)ri[u] * 8;
            q0[u] = *(const float4*)q;   // S_pp, S_p, S_pr, S_r
            q4[u] = q[4];                // S_rr
        }
    }
    #pragma unroll
    for (int u = 0; u < 4; ++u) {
        if (act[u]) {
            const int b = t + u * T;
            const float c = hs[u].x - ts[u].x;   // sum(h) - sum(t)
            const float a = hs[u].y - ts[u].y;   // (hp.h) - (tp.t)
            out[b] = a * a * q0[u].x + c * c * (float)ENT_DIM + q4[u]
                   + 2.0f * (a * c * q0[u].y + a * q0[u].z + c * q0[u].w);
        }
    }
}

// Fallback (only if ws_size is too small): direct wave-per-element compute.
__global__ void direct_kernel(const float* __restrict__ he, const float* __restrict__ hep,
                              const float* __restrict__ te, const float* __restrict__ tep,
                              const float* __restrict__ re, const float* __restrict__ rep,
                              const int* __restrict__ hidx, const int* __restrict__ tidx,
                              const int* __restrict__ ridx,
                              float* __restrict__ out, int B) {
    const int wave = (blockIdx.x * blockDim.x + threadIdx.x) >> 6;
    const int lane = threadIdx.x & 63;
    if (wave >= B) return;
    const int hi = hidx[wave], ti = tidx[wave], ri = ridx[wave];
    const float2 h  = ((const float2*)(he  + (size_t)hi * ENT_DIM))[lane];
    const float2 hp = ((const float2*)(hep + (size_t)hi * ENT_DIM))[lane];
    const float2 t  = ((const float2*)(te  + (size_t)ti * ENT_DIM))[lane];
    const float2 tp = ((const float2*)(tep + (size_t)ti * ENT_DIM))[lane];
    const float2 r  = ((const float2*)(re  + (size_t)ri * ENT_DIM))[lane];
    const float2 rp = ((const float2*)(rep + (size_t)ri * ENT_DIM))[lane];
    float hd = h.x * hp.x + h.y * hp.y;
    float hs = h.x + h.y;
    float td = t.x * tp.x + t.y * tp.y;
    float ts = t.x + t.y;
    #pragma unroll
    for (int off = 32; off >= 1; off >>= 1) {
        hd += __shfl_xor(hd, off, 64);
        hs += __shfl_xor(hs, off, 64);
        td += __shfl_xor(td, off, 64);
        ts += __shfl_xor(ts, off, 64);
    }
    const float a = hd - td, c = hs - ts;
    const float dx = a * rp.x + c + r.x;
    const float dy = a * rp.y + c + r.y;
    float sc = dx * dx + dy * dy;
    #pragma unroll
    for (int off = 32; off >= 1; off >>= 1) sc += __shfl_xor(sc, off, 64);
    if (lane == 0) out[wave] = sc;
}

extern "C" void kernel_launch(void* const* d_in, const int* in_sizes, int n_in,
                              void* d_out, int out_size, void* d_ws, size_t ws_size,
                              hipStream_t stream) {
    const float* he  = (const float*)d_in[0];
    const float* hep = (const float*)d_in[1];
    const float* te  = (const float*)d_in[2];
    const float* tep = (const float*)d_in[3];
    const float* re  = (const float*)d_in[4];
    const float* rep = (const float*)d_in[5];
    const int* hidx  = (const int*)d_in[6];
    const int* tidx  = (const int*)d_in[7];
    const int* ridx  = (const int*)d_in[8];
    float* out = (float*)d_out;

    const int n_nodes = in_sizes[0] / ENT_DIM;   // 200000
    const int n_rels  = in_sizes[4] / ENT_DIM;   // 500
    const int B       = in_sizes[6];             // 500000

    const size_t hstats_bytes = (size_t)n_nodes * sizeof(float2);
    const size_t rstats_bytes = (size_t)n_rels * 8 * sizeof(float);
    const size_t need = 2 * hstats_bytes + rstats_bytes;

    if (ws_size >= need) {
        float2* hstats = (float2*)d_ws;
        float2* tstats = (float2*)((char*)d_ws + hstats_bytes);
        float*  rstats = (float*)((char*)d_ws + 2 * hstats_bytes);

        // Pass 1: 2*n_nodes rows, 8 rows/wave, 4 waves/block.
        const int njobs   = 2 * n_nodes;
        const int waves1  = (njobs + 7) / 8;
        const int blocks1 = (waves1 + 3) / 4;
        node_stats_kernel<<<blocks1, 256, 0, stream>>>(he, hep, te, tep,
                                                       hstats, tstats, n_nodes);
        // Pass 2
        const int blocks2 = (n_rels * 64 + 255) / 256;
        rel_stats_kernel<<<blocks2, 256, 0, stream>>>(re, rep, rstats, n_rels);
        // Pass 3: 4 elements/thread
        const int threads3 = (B + 3) / 4;
        const int blocks3  = (threads3 + 255) / 256;
        score_kernel<<<blocks3, 256, 0, stream>>>(hidx, tidx, ridx,
                                                  hstats, tstats, rstats, out, B);
    } else {
        const int blocks = (B * 64 + 255) / 256;
        direct_kernel<<<blocks, 256, 0, stream>>>(he, hep, te, tep, re, rep,
                                                  hidx, tidx, ridx, out, B);
    }
}